// Round 2
// baseline (318.608 us; speedup 1.0000x reference)
//
#include <hip/hip_runtime.h>

#define BB 256     // batch
#define E 512      // embed channels
#define HDE 512    // h dim
#define HW 256     // spatial (8*32)
#define CATT 512   // attention context channels
#define NT 1024    // threads per block
#define NW (NT / 64)   // 16 waves

// tanh(x) = 1 - 2/(1+exp(2x)); rcp approx (~1e-6 rel) is fine at 5e-4 abs tol.
// Saturation: x>>0 -> exp=inf -> rcp=0 -> 1; x<<0 -> exp=0 -> rcp=1 -> -1.
__device__ __forceinline__ float fast_tanh(float x) {
    float e = __expf(2.0f * x);
    float r = __builtin_amdgcn_rcpf(1.0f + e);
    return 1.0f - 2.0f * r;
}

// One block per batch element. Phases:
//   A: g[e] = Wh[e,:]·h[b,:] + bh[e]           (Wh from L2, 1 MB/block)
//   B: scores[s] = sum_e Wa[e]*tanh(x_em+g)    (x_em stream, 512 KB/block)
//   C: softmax(scores) -> alpha                (block-local)
//   D: att_out[c] = sum_s alpha[s]*att[s,c]    (att stream, 512 KB/block)
__global__ __launch_bounds__(NT, 4) void fused_attn(
        const float* __restrict__ h, const float* __restrict__ x_em,
        const float* __restrict__ att, const float* __restrict__ Wh,
        const float* __restrict__ bh, const float* __restrict__ Wa,
        float* __restrict__ out) {
    const int b = blockIdx.x;
    const int t = threadIdx.x;
    const int lane = t & 63;
    const int w = t >> 6;

    __shared__ float sH[HDE];           // 2 KB
    __shared__ float sG[E];             // 2 KB
    __shared__ float sWa[E];            // 2 KB
    __shared__ float sAlpha[HW];        // 1 KB
    __shared__ float sred[8];
    __shared__ float4 sBuf4[NW * 64];   // 16 KB, reused by phases B and D
    float* sBuf = (float*)sBuf4;

    // stage h[b,:]
    if (t < HDE / 4)
        ((float4*)sH)[t] = ((const float4*)(h + (size_t)b * HDE))[t];
    __syncthreads();

    // ---- Phase A: GEMV, 2 threads per e (split-K halves) ----
    {
        const int e = t >> 1;
        const int half = t & 1;
        const float* wrow = Wh + (size_t)e * HDE + half * (HDE / 2);
        const float* hrow = sH + half * (HDE / 2);
        float acc = 0.0f;
#pragma unroll 8
        for (int i = 0; i < HDE / 8; ++i) {        // 64 float4 per thread
            float4 wv = ((const float4*)wrow)[i];
            float4 hv = ((const float4*)hrow)[i];  // LDS broadcast
            acc += wv.x * hv.x + wv.y * hv.y + wv.z * hv.z + wv.w * hv.w;
        }
        acc += __shfl_xor(acc, 1);
        if (half == 0) {
            sG[e] = acc + bh[e];
            sWa[e] = Wa[e];
        }
    }
    __syncthreads();

    // ---- Phase B: per-wave partial scores; wave w owns e in [w*32, w*32+32) ----
    {
        const float* xb = x_em + ((size_t)b * E + (size_t)w * (E / NW)) * HW + lane * 4;
        float4 acc = {0.f, 0.f, 0.f, 0.f};
#pragma unroll 8
        for (int i = 0; i < E / NW; ++i) {         // 32 rows, 1 KB coalesced each
            float4 x = *(const float4*)(xb + (size_t)i * HW);
            const int e = w * (E / NW) + i;
            const float g = sG[e];                 // LDS broadcast
            const float wa = sWa[e];
            acc.x += wa * fast_tanh(x.x + g);
            acc.y += wa * fast_tanh(x.y + g);
            acc.z += wa * fast_tanh(x.z + g);
            acc.w += wa * fast_tanh(x.w + g);
        }
        sBuf4[w * 64 + lane] = acc;                // sBuf[w*256 + s]
    }
    __syncthreads();

    // ---- Phase C: reduce 16 wave-partials, softmax over 256 ----
    float v = 0.f, p = 0.f;
    if (t < HW) {
        #pragma unroll
        for (int g = 0; g < NW; ++g) v += sBuf[g * HW + t];
        float m = v;
        #pragma unroll
        for (int o = 32; o; o >>= 1) m = fmaxf(m, __shfl_xor(m, o));
        if (lane == 0) sred[w] = m;                // w in 0..3 here
    }
    __syncthreads();
    if (t < HW) {
        float m = fmaxf(fmaxf(sred[0], sred[1]), fmaxf(sred[2], sred[3]));
        p = __expf(v - m);
        float s = p;
        #pragma unroll
        for (int o = 32; o; o >>= 1) s += __shfl_xor(s, o);
        if (lane == 0) sred[4 + w] = s;
    }
    __syncthreads();
    if (t < HW) {
        float s = sred[4] + sred[5] + sred[6] + sred[7];
        float a = p / s;
        sAlpha[t] = a;
        out[(size_t)BB * CATT + (size_t)b * HW + t] = a;   // alpha output
    }
    __syncthreads();

    // ---- Phase D: att_out partials; 8 groups of 128 threads over c, split s ----
    {
        const int c4 = t & 127;                    // float4 index over CATT
        const int g = t >> 7;                      // 0..7
        const float* ab = att + ((size_t)b * HW + g) * CATT + c4 * 4;
        float4 acc = {0.f, 0.f, 0.f, 0.f};
#pragma unroll 8
        for (int i = 0; i < HW / 8; ++i) {         // 32 rows per group
            float4 x = *(const float4*)(ab + (size_t)i * 8 * CATT);
            const float a = sAlpha[g + i * 8];     // LDS broadcast
            acc.x += a * x.x;
            acc.y += a * x.y;
            acc.z += a * x.z;
            acc.w += a * x.w;
        }
        sBuf4[g * 128 + c4] = acc;                 // exactly fills 1024 float4s
    }
    __syncthreads();

    // ---- reduce 8 group-partials, store att_out ----
    if (t < CATT / 4) {
        float4 acc = sBuf4[t];
        #pragma unroll
        for (int g = 1; g < 8; ++g) {
            float4 x = sBuf4[g * 128 + t];
            acc.x += x.x; acc.y += x.y; acc.z += x.z; acc.w += x.w;
        }
        ((float4*)(out + (size_t)b * CATT))[t] = acc;
    }
}

extern "C" void kernel_launch(void* const* d_in, const int* in_sizes, int n_in,
                              void* d_out, int out_size, void* d_ws, size_t ws_size,
                              hipStream_t stream) {
    const float* h    = (const float*)d_in[0];
    const float* x_em = (const float*)d_in[1];
    const float* att  = (const float*)d_in[2];
    const float* Wh   = (const float*)d_in[3];
    const float* bh   = (const float*)d_in[4];
    const float* Wa   = (const float*)d_in[5];
    // d_in[6] = ba: cancels in softmax (shift invariance); outputs don't use scores.

    float* out = (float*)d_out;   // [BB*CATT] att_out, then [BB*HW] alpha

    fused_attn<<<dim3(BB), NT, 0, stream>>>(h, x_em, att, Wh, bh, Wa, out);
}

// Round 3
// 315.713 us; speedup vs baseline: 1.0092x; 1.0092x over previous
//
#include <hip/hip_runtime.h>

#define BB 256     // batch
#define E 512      // embed channels
#define HDE 512    // h dim
#define HW 256     // spatial (8*32)
#define CATT 512   // attention context channels
#define Q 4        // split factor (blocks per batch element per kernel)
#define ECH (E / Q)     // 128 e-channels per K1 block
#define CCH (CATT / Q)  // 128 c-channels per K2 block

// tanh(x) = 1 - 2/(1+exp(2x)); rcp approx ok at 5e-4 tol; saturates correctly.
__device__ __forceinline__ float fast_tanh(float x) {
    float e = __expf(2.0f * x);
    float r = __builtin_amdgcn_rcpf(1.0f + e);
    return 1.0f - 2.0f * r;
}

// ---------------- K1: g-slice GEMV + tanh-weighted channel partial sum -------
// grid (BB, Q), block 256 (4 waves). Block (b,q) owns e in [q*128, q*128+128).
__global__ __launch_bounds__(256, 8) void k_scores(
        const float* __restrict__ h, const float* __restrict__ x_em,
        const float* __restrict__ Wh, const float* __restrict__ bh,
        const float* __restrict__ Wa, float* __restrict__ scoresPart) {
    const int b = blockIdx.x, q = blockIdx.y;
    const int t = threadIdx.x, lane = t & 63, w = t >> 6;

    __shared__ float sG[ECH];
    __shared__ float sWa[ECH];
    __shared__ float4 sPart[4][HW / 4];

    // lane's fixed h chunk (registers; broadcast-friendly L1/L2 across blocks)
    const float* hp = h + (size_t)b * HDE + lane * 8;
    const float4 h0 = *(const float4*)hp;
    const float4 h1 = *(const float4*)(hp + 4);

    // GEMV, wave-per-row: wave w handles rows el = w*32 .. w*32+31.
    // Wh row read is fully coalesced: 64 lanes x 32B = 2 KB contiguous.
#pragma unroll 4
    for (int i = 0; i < 32; ++i) {
        const int el = w * 32 + i;
        const int e = q * ECH + el;
        const float* wr = Wh + (size_t)e * HDE + lane * 8;
        float4 w0 = *(const float4*)wr;
        float4 w1 = *(const float4*)(wr + 4);
        float acc = w0.x * h0.x + w0.y * h0.y + w0.z * h0.z + w0.w * h0.w
                  + w1.x * h1.x + w1.y * h1.y + w1.z * h1.z + w1.w * h1.w;
#pragma unroll
        for (int o = 32; o; o >>= 1) acc += __shfl_xor(acc, o);
        if (lane == 0) {
            sG[el] = acc + bh[e];
            sWa[el] = Wa[e];
        }
    }
    __syncthreads();

    // Stream x_em rows for this e-range: wave w reads rows w*32..w*32+31,
    // each row = 1 KB fully coalesced (64 lanes x float4).
    {
        const float* xb = x_em + ((size_t)b * E + (size_t)q * ECH + (size_t)w * 32) * HW
                        + (size_t)lane * 4;
        float4 acc = {0.f, 0.f, 0.f, 0.f};
#pragma unroll 8
        for (int i = 0; i < 32; ++i) {
            float4 x = *(const float4*)(xb + (size_t)i * HW);
            const float g = sG[w * 32 + i];
            const float wa = sWa[w * 32 + i];
            acc.x += wa * fast_tanh(x.x + g);
            acc.y += wa * fast_tanh(x.y + g);
            acc.z += wa * fast_tanh(x.z + g);
            acc.w += wa * fast_tanh(x.w + g);
        }
        sPart[w][lane] = acc;
    }
    __syncthreads();

    if (t < HW / 4) {
        float4 a0 = sPart[0][t], a1 = sPart[1][t], a2 = sPart[2][t], a3 = sPart[3][t];
        float4 r;
        r.x = a0.x + a1.x + a2.x + a3.x;
        r.y = a0.y + a1.y + a2.y + a3.y;
        r.z = a0.z + a1.z + a2.z + a3.z;
        r.w = a0.w + a1.w + a2.w + a3.w;
        *(float4*)(scoresPart + ((size_t)q * BB + b) * HW + t * 4) = r;
    }
}

// ---------------- K2: reduce partials + softmax + alpha-weighted att sum -----
// grid (BB, Q), block 256. Block (b,q) owns c in [q*128, q*128+128).
// Softmax recomputed per block (cheap: 4 KB read, 256-wide reduce).
__global__ __launch_bounds__(256, 8) void k_att(
        const float* __restrict__ scoresPart, const float* __restrict__ att,
        float* __restrict__ out) {
    const int b = blockIdx.x, q = blockIdx.y;
    const int t = threadIdx.x, lane = t & 63, w = t >> 6;

    __shared__ float sAlpha[HW];
    __shared__ float sred[8];
    __shared__ float4 sPar[8][CCH / 4];

    // reduce Q score partials; thread t owns s = t
    float v = 0.f;
#pragma unroll
    for (int p = 0; p < Q; ++p)
        v += scoresPart[((size_t)p * BB + b) * HW + t];

    // softmax over 256 (4 waves)
    float m = v;
#pragma unroll
    for (int o = 32; o; o >>= 1) m = fmaxf(m, __shfl_xor(m, o));
    if (lane == 0) sred[w] = m;
    __syncthreads();
    m = fmaxf(fmaxf(sred[0], sred[1]), fmaxf(sred[2], sred[3]));
    float p = __expf(v - m);
    float s = p;
#pragma unroll
    for (int o = 32; o; o >>= 1) s += __shfl_xor(s, o);
    if (lane == 0) sred[4 + w] = s;
    __syncthreads();
    s = sred[4] + sred[5] + sred[6] + sred[7];
    const float a = p / s;
    sAlpha[t] = a;
    if (q == 0) out[(size_t)BB * CATT + (size_t)b * HW + t] = a;  // alpha
    __syncthreads();

    // att stream: thread (c4 = t&31, sg = t>>5); group sg reads rows sg+8i.
    // Each wave-load = 2 rows x 512B contiguous segments.
    {
        const int c4 = t & 31, sg = t >> 5;
        const float* ab = att + ((size_t)b * HW + sg) * CATT + (size_t)q * CCH + c4 * 4;
        float4 acc = {0.f, 0.f, 0.f, 0.f};
#pragma unroll 8
        for (int i = 0; i < 32; ++i) {
            float4 x = *(const float4*)(ab + (size_t)(8 * i) * CATT);
            const float al = sAlpha[sg + 8 * i];
            acc.x += al * x.x;
            acc.y += al * x.y;
            acc.z += al * x.z;
            acc.w += al * x.w;
        }
        sPar[sg][c4] = acc;
    }
    __syncthreads();

    if (t < CCH / 4) {
        float4 r = sPar[0][t];
#pragma unroll
        for (int g = 1; g < 8; ++g) {
            float4 x = sPar[g][t];
            r.x += x.x; r.y += x.y; r.z += x.z; r.w += x.w;
        }
        *(float4*)(out + (size_t)b * CATT + (size_t)q * CCH + t * 4) = r;
    }
}

extern "C" void kernel_launch(void* const* d_in, const int* in_sizes, int n_in,
                              void* d_out, int out_size, void* d_ws, size_t ws_size,
                              hipStream_t stream) {
    const float* h    = (const float*)d_in[0];
    const float* x_em = (const float*)d_in[1];
    const float* att  = (const float*)d_in[2];
    const float* Wh   = (const float*)d_in[3];
    const float* bh   = (const float*)d_in[4];
    const float* Wa   = (const float*)d_in[5];
    // d_in[6] = ba: cancels in softmax (shift invariance).

    float* out = (float*)d_out;          // [BB*CATT] att_out, then [BB*HW] alpha
    float* scoresPart = (float*)d_ws;    // Q*BB*HW floats = 1 MB

    k_scores<<<dim3(BB, Q), 256, 0, stream>>>(h, x_em, Wh, bh, Wa, scoresPart);
    k_att<<<dim3(BB, Q), 256, 0, stream>>>(scoresPart, att, out);
}